// Round 13
// baseline (116.524 us; speedup 1.0000x reference)
//
#include <hip/hip_runtime.h>
#include <math.h>

#define BSZ    8192
#define DDIM   256
#define SCALE  33.33333333333333f   // 1/0.03
#define C_OFF  34.0f                // fixed LSE offset: |sim*SCALE| <= 33.34
#define SC_L2E 48.08983470f         // SCALE * log2(e)
#define C2     49.05163139f         // C_OFF * log2(e)

typedef float floatx4  __attribute__((ext_vector_type(4)));
typedef float floatx16 __attribute__((ext_vector_type(16)));
typedef int   intx4    __attribute__((ext_vector_type(4)));
typedef int   intx8    __attribute__((ext_vector_type(8)));
typedef long long fp8x8;            // 8 x fp8 e4m3

// pack 8 fp32 -> 8 fp8 e4m3 (HW cvt; format matches the fp8 MFMA operand)
__device__ __forceinline__ fp8x8 cvt8_f8(const float* __restrict__ g)
{
    const float4 lo = *(const float4*)g;
    const float4 hi = *(const float4*)(g + 4);
    int a = __builtin_amdgcn_cvt_pk_fp8_f32(lo.x, lo.y, 0, false);
    a     = __builtin_amdgcn_cvt_pk_fp8_f32(lo.z, lo.w, a, true);
    int b = __builtin_amdgcn_cvt_pk_fp8_f32(hi.x, hi.y, 0, false);
    b     = __builtin_amdgcn_cvt_pk_fp8_f32(hi.z, hi.w, b, true);
    int2 r; r.x = a; r.y = b;
    return *(fp8x8*)&r;
}

// ---------------------------------------------------------------- prep (R11/R12-identical)
// za_f8: row-major [8192][256] fp8.
// zt_perm operand-major layout:
//   byte(cb, o, lane, part) = cb*32768 + o*2048 + lane*32 + part*8, o = ks*4+n.
//   Lane l of operand (ks,n): col = cb*128 + n*32 + (l&31),
//   k = ks*64 + (l>>5)*32 + part*8 .. +8  (= HW B-operand layout for
//   mfma_scale_32x32x64; verified absmax 0.0 in R11/R12).
__global__ __launch_bounds__(256) void prep_kernel(
    const float* __restrict__ za, const float* __restrict__ zt,
    unsigned char* __restrict__ za_f8, unsigned char* __restrict__ zt_perm,
    float* __restrict__ zbase)
{
    const int bid = blockIdx.x, tid = threadIdx.x;
    if (bid < 1024) {
        const int i = (bid * 256 + tid) * 8;
        *(fp8x8*)(za_f8 + i) = cvt8_f8(za + i);
        if (bid < 16) {
            const int z = bid * 1024 + tid * 4;
            *(float4*)&zbase[z] = (float4){0.f, 0.f, 0.f, 0.f};
            if (bid == 0 && tid == 0) {
                zbase[16384] = 0.f;          // total
                ((int*)zbase)[16385] = 0;    // flag
                ((int*)zbase)[16386] = 0;    // cnt
            }
        }
    } else {
        const int S    = (bid - 1024) * 256 + tid;   // global 8-B slot id
        const int cbb  = S >> 12;                    // col-block 0..63
        const int r    = S & 4095;                   // slot within cb (32KB)
        const int o    = r >> 8;                     // operand 0..15 (2KB each)
        const int w    = r & 255;                    // slot within operand
        const int ln   = w >> 2;                     // lane 0..63
        const int part = w & 3;                      // 8B part 0..3
        const int ks   = o >> 2, n = o & 3;
        const int col  = cbb * 128 + n * 32 + (ln & 31);
        const int k    = ks * 64 + (ln >> 5) * 32 + part * 8;
        const float* src = zt + (size_t)col * DDIM + k;
        *(fp8x8*)(zt_perm + (size_t)S * 8) = cvt8_f8(src);
    }
}

// ---------------------------------------------------------------- sim
// ROUND-13: R12 + inline-asm RESIDENCY PIN on bf.
// R12 post-mortem: launch_bounds(256,1) didn't help — VGPR stayed 160.
// The 160 is not a cap: the allocator's REMAT heuristic re-loads bf from
// L2 every tile rather than keeping 128 regs live (3rd blocked attempt:
// R5 remat-A, R11 heuristic, R12 remat-despite-budget). Fix: empty asm
// with "+v" on each bf operand — the value becomes asm-DEFINED (opaque,
// non-rematerializable) so it MUST stay resident (or visibly spill).
// If it binds: K-loop = 16 register-only mfma_scale/tile, zero memory ops,
// zero LDS pipe; only A (32B/lane/tile, L2-hot) + pid traffic remains.
// Tripwires: VGPR_Count >= 224 (else pin failed); FETCH ~9.7MB / WRITE
// ~2.3MB unchanged (else scratch spill); absmax 0.0.
// Decision rule: null or worse -> revert to R8 (102.0us) as final.
__global__ __launch_bounds__(256, 1) void sim_fused(
    const unsigned char* __restrict__ za_f8, const unsigned char* __restrict__ zt_perm,
    const int* __restrict__ pid,
    float* __restrict__ s_row, float* __restrict__ s_col,
    float* __restrict__ posv)
{
    __shared__ int   pidc[128];
    __shared__ float colsum[128];

    const int bid   = blockIdx.x;
    const int cbb   = bid & 63;          // column block (fixed for this block)
    const int bgrp  = bid >> 6;          // 0..7 -> bands bgrp*8 .. bgrp*8+7
    const int col0g = cbb * 128;
    const int tid   = threadIdx.x, lane = tid & 63, wid = tid >> 6;
    const int l31   = lane & 31, h = lane >> 5;

    if (tid < 128) { pidc[tid] = pid[col0g + tid]; colsum[tid] = 0.f; }

    // ---- load ALL of B into registers: 16 operands x 32B/lane = 128 VGPR
    intx8 bf[4][4];
    {
        const unsigned char* gb = zt_perm + (size_t)cbb * 32768 + lane * 32;
        #pragma unroll
        for (int ks = 0; ks < 4; ks++)
            #pragma unroll
            for (int n = 0; n < 4; n++)
                bf[ks][n] = *(const intx8*)(gb + (ks * 4 + n) * 2048);
    }
    // RESIDENCY PIN: asm-define each operand -> cannot be rematerialized.
    #pragma unroll
    for (int ks = 0; ks < 4; ks++)
        #pragma unroll
        for (int n = 0; n < 4; n++)
            __asm__ volatile("" : "+v"(bf[ks][n]));

    __syncthreads();   // pidc/colsum visible. ONLY barrier until the final flush.

    // col pids (tile-invariant)
    int pc[4];
    #pragma unroll
    for (int n = 0; n < 4; n++) pc[n] = pidc[n * 32 + l31];

    const int band0 = bgrp * 8;
    float colp4[4] = {0.f, 0.f, 0.f, 0.f};   // accumulates across ALL 8 tiles
    const int  target = (lane & 3) + 4 * ((lane >> 3) & 3);  // reg holding diag
    const bool ownl   = (h == ((lane >> 2) & 1));            // h matches row bit2

    #pragma unroll
    for (int i = 0; i < 8; i++) {
        const int band  = band0 + i;
        const int rbase = band * 128 + wid * 32;

        // A fragments for this tile (L2-hot; covered by the co-wave's MFMAs)
        intx8 afc[4];
        {
            const unsigned char* ga =
                za_f8 + (size_t)(rbase + l31) * DDIM + h * 32;
            #pragma unroll
            for (int ks = 0; ks < 4; ks++)
                afc[ks] = *(const intx8*)(ga + ks * 64);
        }

        // row pids for this tile (epilogue-only use)
        int prw[16];
        #pragma unroll
        for (int reg = 0; reg < 16; reg++)
            prw[reg] = pid[rbase + (reg & 3) + 8 * (reg >> 2) + 4 * h];

        // ---- GEMM: 16 register-only mfma_scale (zero memory ops)
        floatx16 acc[4];
        #pragma unroll
        for (int n = 0; n < 4; n++) acc[n] = (floatx16)0.0f;

        #pragma unroll
        for (int ks = 0; ks < 4; ks++)
            #pragma unroll
            for (int n = 0; n < 4; n++)
                acc[n] = __builtin_amdgcn_mfma_scale_f32_32x32x64_f8f6f4(
                    afc[ks], bf[ks][n], acc[n], 0, 0, 0,
                    0x7F7F7F7F, 0, 0x7F7F7F7F);

        // ---- epilogue (wave-local, no syncs)
        float rowp[16];
        #pragma unroll
        for (int r = 0; r < 16; r++) rowp[r] = 0.f;

        #pragma unroll
        for (int n = 0; n < 4; n++) {
            const int pcn = pc[n];
            #pragma unroll
            for (int reg = 0; reg < 16; reg++) {
                float e = __builtin_amdgcn_exp2f(fmaf(acc[n][reg], SC_L2E, -C2));
                e = (prw[reg] != pcn) ? e : 0.f;
                colp4[n] += e;
                rowp[reg] += e;
            }
            if (band == cbb && n == wid) {   // diagonal fixup (wave-uniform)
                float vd = 0.f;
                #pragma unroll
                for (int reg = 0; reg < 16; reg++)
                    vd = (reg == target) ? acc[n][reg] : vd;   // cndmask chain
                float ed = __builtin_amdgcn_exp2f(fmaf(vd, SC_L2E, -C2));
                ed = ownl ? ed : 0.f;
                colp4[n] += ed;
                #pragma unroll
                for (int reg = 0; reg < 16; reg++)
                    rowp[reg] += (reg == target) ? ed : 0.f;   // ed=0 if !ownl
                if (ownl) posv[band * 128 + wid * 32 + l31] = vd * SCALE;
            }
        }

        // row sums: split-tree reduce of rowp[16] over the 32-lane half
#define RED(bit, c)                                                        \
        _Pragma("unroll")                                                  \
        for (int _i = 0; _i < (c); _i++) {                                 \
            float _s = (lane & (bit)) ? rowp[_i] : rowp[_i + (c)];         \
            float _o = __shfl_xor(_s, (bit), 64);                          \
            rowp[_i] = ((lane & (bit)) ? rowp[_i + (c)] : rowp[_i]) + _o;  \
        }
        RED(1, 8) RED(2, 4) RED(4, 2) RED(8, 1)
#undef RED
        rowp[0] += __shfl_xor(rowp[0], 16, 64);
        if ((lane & 16) == 0) {
            const int reg = ((lane & 1) << 3) | ((lane & 2) << 1)
                          | ((lane & 4) >> 1) | ((lane & 8) >> 3);
            const int rl  = (reg & 3) + 8 * (reg >> 2) + 4 * h;
            atomicAdd(&s_row[rbase + rl], rowp[0]);
        }
    }

    // ---- col flush (once per block, after all 8 tiles)
    #pragma unroll
    for (int n = 0; n < 4; n++)
        colp4[n] += __shfl_xor(colp4[n], 32, 64);
    if (lane < 32) {
        #pragma unroll
        for (int n = 0; n < 4; n++)
            atomicAdd(&colsum[n * 32 + lane], colp4[n]);
    }
    __syncthreads();
    if (tid < 128) atomicAdd(&s_col[col0g + tid], colsum[tid]);
}

// ---------------------------------------------------------------- finalize (+ scalar write)
__global__ __launch_bounds__(256) void finalize_rows(
    const int* __restrict__ pid,
    const float* __restrict__ s_row, const float* __restrict__ s_col,
    const float* __restrict__ posv,
    float* __restrict__ total, int* __restrict__ flag, int* __restrict__ cnt,
    float* __restrict__ out)
{
    const int i = blockIdx.x * 256 + threadIdx.x;
    const float p = posv[i];
    const float c = (logf(s_row[i]) + C_OFF - p)
                  + (logf(s_col[i]) + C_OFF - p);

    float v = c;
    #pragma unroll
    for (int off = 32; off > 0; off >>= 1) v += __shfl_down(v, off, 64);
    if ((threadIdx.x & 63) == 0) atomicAdd(total, v);

    const unsigned long long m = __ballot(pid[i] != pid[0]);
    if (m != 0ull && (threadIdx.x & 63) == 0) atomicOr(flag, 1);

    __syncthreads();
    __threadfence();
    if (threadIdx.x == 0) {
        const int done = atomicAdd(cnt, 1);
        if (done == (int)gridDim.x - 1) {
            const float t = atomicAdd(total, 0.0f);
            const int   f = atomicOr(flag, 0);
            out[0] = f ? t / (2.0f * (float)BSZ) : 0.0f;
        }
    }
}

// ---------------------------------------------------------------- launcher
extern "C" void kernel_launch(void* const* d_in, const int* in_sizes, int n_in,
                              void* d_out, int out_size, void* d_ws, size_t ws_size,
                              hipStream_t stream)
{
    const float* za  = (const float*)d_in[0];
    const float* zt  = (const float*)d_in[1];
    const int*   pid = (const int*)d_in[2];
    float* out = (float*)d_out;

    // ws: za_f8 2MB | zt_perm 2MB | s_row[8192] s_col[8192] total flag cnt posv[8192]
    unsigned char* za_f8   = (unsigned char*)d_ws;
    unsigned char* zt_perm = za_f8 + (size_t)BSZ * DDIM;
    float*  s_row   = (float*)(zt_perm + (size_t)BSZ * DDIM);
    float*  s_col   = s_row + BSZ;
    float*  total   = s_col + BSZ;
    int*    flag    = (int*)(total + 1);
    int*    cnt     = flag + 1;
    float*  posv    = (float*)(cnt + 1);

    prep_kernel<<<dim3(2048), 256, 0, stream>>>(za, zt, za_f8, zt_perm, s_row);

    sim_fused<<<dim3(512), 256, 0, stream>>>(za_f8, zt_perm, pid,
                                             s_row, s_col, posv);

    finalize_rows<<<dim3(BSZ / 256), 256, 0, stream>>>(
        pid, s_row, s_col, posv, total, flag, cnt, out);
}

// Round 14
// 103.094 us; speedup vs baseline: 1.1303x; 1.1303x over previous
//
#include <hip/hip_runtime.h>
#include <math.h>

#define BSZ    8192
#define DDIM   256
#define SCALE  33.33333333333333f   // 1/0.03
#define C_OFF  34.0f                // fixed LSE offset: |sim*SCALE| <= 33.34
#define SC_L2E 48.08983470f         // SCALE * log2(e)
#define C2     49.05163139f         // C_OFF * log2(e)

typedef float floatx4  __attribute__((ext_vector_type(4)));
typedef float floatx16 __attribute__((ext_vector_type(16)));
typedef int   intx4    __attribute__((ext_vector_type(4)));
typedef int   intx8    __attribute__((ext_vector_type(8)));
typedef long long fp8x8;            // 8 x fp8 e4m3

// pack 8 fp32 -> 8 fp8 e4m3 (HW cvt; format matches the fp8 MFMA operand)
__device__ __forceinline__ fp8x8 cvt8_f8(const float* __restrict__ g)
{
    const float4 lo = *(const float4*)g;
    const float4 hi = *(const float4*)(g + 4);
    int a = __builtin_amdgcn_cvt_pk_fp8_f32(lo.x, lo.y, 0, false);
    a     = __builtin_amdgcn_cvt_pk_fp8_f32(lo.z, lo.w, a, true);
    int b = __builtin_amdgcn_cvt_pk_fp8_f32(hi.x, hi.y, 0, false);
    b     = __builtin_amdgcn_cvt_pk_fp8_f32(hi.z, hi.w, b, true);
    int2 r; r.x = a; r.y = b;
    return *(fp8x8*)&r;
}

// ---------------------------------------------------------------- prep (R7/R8-identical)
// za_f8: row-major [8192][256] fp8.
// zt_perm layout: byte(cb,col,gph,off) = cb*32768 + col*256 + gph*16 + off;
// physical granule gph holds LOGICAL k-granule kg = gph ^ (col&15).
__global__ __launch_bounds__(256) void prep_kernel(
    const float* __restrict__ za, const float* __restrict__ zt,
    unsigned char* __restrict__ za_f8, unsigned char* __restrict__ zt_perm,
    float* __restrict__ zbase)
{
    const int bid = blockIdx.x, tid = threadIdx.x;
    if (bid < 1024) {
        const int i = (bid * 256 + tid) * 8;
        *(fp8x8*)(za_f8 + i) = cvt8_f8(za + i);
        if (bid < 16) {
            const int z = bid * 1024 + tid * 4;
            *(float4*)&zbase[z] = (float4){0.f, 0.f, 0.f, 0.f};
            if (bid == 0 && tid == 0) {
                zbase[16384] = 0.f;          // total
                ((int*)zbase)[16385] = 0;    // flag
                ((int*)zbase)[16386] = 0;    // cnt
            }
        }
    } else {
        const int S    = (bid - 1024) * 256 + tid;   // global 8-B slot id
        const int cbb  = S >> 12;                    // col-block 0..63
        const int col  = (S >> 5) & 127;             // col within block
        const int gph  = (S >> 1) & 15;              // physical 16B granule
        const int off8 = (S & 1) * 8;
        const int k    = ((gph ^ (col & 15)) << 4) + off8;  // logical k byte
        const float* src = zt + (size_t)(cbb * 128 + col) * DDIM + k;
        *(fp8x8*)(zt_perm + (size_t)S * 8) = cvt8_f8(src);
    }
}

// ---------------------------------------------------------------- sim
// ROUND-14: EXACT REVERT TO R8 — the session's verified best (102.0us,
// absmax 0.0; steady sim ~35us by the total-minus-66.8 overhead model).
// Why R8 stands: the only A/B win of 14 rounds (persistent blocks, B
// staged ONCE and pinned in LDS, zero K-loop barriers, reg-accumulated
// colsums, A prefetched one tile ahead). Everything else measured null or
// worse: barrier elimination (R2/R4/R6), 2x occupancy (R9), 2.3x MFMA rate
// (R7 — sim unchanged, not MFMA-bound), grid-barrier fusion (R10, -29us),
// register-resident B (R11-R13 — allocator remats; untestable at source
// level). Remaining budget: harness fill 43us (uncontrollable) + sim ~35
// + prep ~10 + finalize ~5 + launches ~10.
// Expected counters: VGPR 128, LDS 33792, FETCH ~9.9MB, total ~102us.
__global__ __launch_bounds__(256, 2) void sim_fused(
    const unsigned char* __restrict__ za_f8, const unsigned char* __restrict__ zt_perm,
    const int* __restrict__ pid,
    float* __restrict__ s_row, float* __restrict__ s_col,
    float* __restrict__ posv)
{
    __shared__ __align__(16) unsigned char Bs[32768];   // 128 cols x 256 k fp8
    __shared__ int   pidc[128];
    __shared__ float colsum[128];

    const int bid   = blockIdx.x;
    const int cbb   = bid & 63;          // column block (fixed for this block)
    const int bgrp  = bid >> 6;          // 0..7 -> bands bgrp*8 .. bgrp*8+7
    const int col0g = cbb * 128;
    const int tid   = threadIdx.x, lane = tid & 63, wid = tid >> 6;
    const int l31   = lane & 31, h = lane >> 5;

    if (tid < 128) { pidc[tid] = pid[col0g + tid]; colsum[tid] = 0.f; }

    // ---- stage B once: 32KB, 4 waves x 8KB, width-16 global_load_lds
    {
        const unsigned char* src = zt_perm + (size_t)cbb * 32768 + wid * 8192 + lane * 16;
        unsigned char* dst = Bs + wid * 8192 + lane * 16;
        #pragma unroll
        for (int i = 0; i < 8; i++)
            __builtin_amdgcn_global_load_lds(
                (const __attribute__((address_space(1))) void*)(src + i * 1024),
                (__attribute__((address_space(3))) void*)(dst + i * 1024),
                16, 0, 0);
    }

    // ---- tile-0 A fragments (prefetch while staging is in flight)
    const int band0 = bgrp * 8;
    intx8 afc[4];
    {
        const unsigned char* ga =
            za_f8 + (size_t)(band0 * 128 + wid * 32 + l31) * DDIM + h * 32;
        #pragma unroll
        for (int ks = 0; ks < 4; ks++)
            afc[ks] = *(const intx8*)(ga + ks * 64);
    }

    __syncthreads();   // B + pidc visible. ONLY barrier until the final flush.

    // ds_read bases for B (fixed across all 8 tiles)
    const int t16 = ((((lane >> 4) & 2) ^ (lane & 15)) << 4);  // ((2h)^s)<<4
    int dsb[4];
    #pragma unroll
    for (int n = 0; n < 4; n++)
        dsb[n] = n * 8192 + l31 * 256 + t16;

    // col pids (tile-invariant)
    int pc[4];
    #pragma unroll
    for (int n = 0; n < 4; n++) pc[n] = pidc[n * 32 + l31];

    float colp4[4] = {0.f, 0.f, 0.f, 0.f};   // accumulates across ALL 8 tiles
    const int  target = (lane & 3) + 4 * ((lane >> 3) & 3);  // reg holding diag
    const bool ownl   = (h == ((lane >> 2) & 1));            // h matches row bit2

    #pragma unroll
    for (int i = 0; i < 8; i++) {
        const int band  = band0 + i;
        const int rbase = band * 128 + wid * 32;

        // prefetch NEXT tile's A (issued before MFMAs -> latency hidden)
        intx8 afn[4];
        if (i < 7) {
            const unsigned char* ga =
                za_f8 + (size_t)(rbase + 128 + l31) * DDIM + h * 32;
            #pragma unroll
            for (int ks = 0; ks < 4; ks++)
                afn[ks] = *(const intx8*)(ga + ks * 64);
        }

        // row pids for this tile (used only in epilogue -> load covered by MFMAs)
        int prw[16];
        #pragma unroll
        for (int reg = 0; reg < 16; reg++)
            prw[reg] = pid[rbase + (reg & 3) + 8 * (reg >> 2) + 4 * h];

        // ---- GEMM: 32 ds_read_b128 + 16 mfma_scale
        floatx16 acc[4];
        #pragma unroll
        for (int n = 0; n < 4; n++) acc[n] = (floatx16)0.0f;

        #pragma unroll
        for (int ks = 0; ks < 4; ks++) {
            #pragma unroll
            for (int n = 0; n < 4; n++) {
                intx8 b;
                *(intx4*)&b =
                    *(const intx4*)(Bs + (dsb[n] ^ ((ks * 4 + 0) << 4)));
                *(((intx4*)&b) + 1) =
                    *(const intx4*)(Bs + (dsb[n] ^ ((ks * 4 + 1) << 4)));
                acc[n] = __builtin_amdgcn_mfma_scale_f32_32x32x64_f8f6f4(
                    afc[ks], b, acc[n], 0, 0, 0, 0x7F7F7F7F, 0, 0x7F7F7F7F);
            }
        }

        // ---- epilogue (wave-local, no syncs)
        float rowp[16];
        #pragma unroll
        for (int r = 0; r < 16; r++) rowp[r] = 0.f;

        #pragma unroll
        for (int n = 0; n < 4; n++) {
            const int pcn = pc[n];
            #pragma unroll
            for (int reg = 0; reg < 16; reg++) {
                float e = __builtin_amdgcn_exp2f(fmaf(acc[n][reg], SC_L2E, -C2));
                e = (prw[reg] != pcn) ? e : 0.f;
                colp4[n] += e;
                rowp[reg] += e;
            }
            if (band == cbb && n == wid) {   // diagonal fixup (wave-uniform)
                float vd = 0.f;
                #pragma unroll
                for (int reg = 0; reg < 16; reg++)
                    vd = (reg == target) ? acc[n][reg] : vd;   // cndmask chain
                float ed = __builtin_amdgcn_exp2f(fmaf(vd, SC_L2E, -C2));
                ed = ownl ? ed : 0.f;
                colp4[n] += ed;
                #pragma unroll
                for (int reg = 0; reg < 16; reg++)
                    rowp[reg] += (reg == target) ? ed : 0.f;   // ed=0 if !ownl
                if (ownl) posv[band * 128 + wid * 32 + l31] = vd * SCALE;
            }
        }

        // row sums: split-tree reduce of rowp[16] over the 32-lane half
#define RED(bit, c)                                                        \
        _Pragma("unroll")                                                  \
        for (int _i = 0; _i < (c); _i++) {                                 \
            float _s = (lane & (bit)) ? rowp[_i] : rowp[_i + (c)];         \
            float _o = __shfl_xor(_s, (bit), 64);                          \
            rowp[_i] = ((lane & (bit)) ? rowp[_i + (c)] : rowp[_i]) + _o;  \
        }
        RED(1, 8) RED(2, 4) RED(4, 2) RED(8, 1)
#undef RED
        rowp[0] += __shfl_xor(rowp[0], 16, 64);
        if ((lane & 16) == 0) {
            const int reg = ((lane & 1) << 3) | ((lane & 2) << 1)
                          | ((lane & 4) >> 1) | ((lane & 8) >> 3);
            const int rl  = (reg & 3) + 8 * (reg >> 2) + 4 * h;
            atomicAdd(&s_row[rbase + rl], rowp[0]);
        }

        // rotate pipelined A
        if (i < 7) {
            #pragma unroll
            for (int ks = 0; ks < 4; ks++) afc[ks] = afn[ks];
        }
    }

    // ---- col flush (once per block, after all 8 tiles)
    #pragma unroll
    for (int n = 0; n < 4; n++)
        colp4[n] += __shfl_xor(colp4[n], 32, 64);
    if (lane < 32) {
        #pragma unroll
        for (int n = 0; n < 4; n++)
            atomicAdd(&colsum[n * 32 + lane], colp4[n]);
    }
    __syncthreads();
    if (tid < 128) atomicAdd(&s_col[col0g + tid], colsum[tid]);
}

// ---------------------------------------------------------------- finalize (+ scalar write)
__global__ __launch_bounds__(256) void finalize_rows(
    const int* __restrict__ pid,
    const float* __restrict__ s_row, const float* __restrict__ s_col,
    const float* __restrict__ posv,
    float* __restrict__ total, int* __restrict__ flag, int* __restrict__ cnt,
    float* __restrict__ out)
{
    const int i = blockIdx.x * 256 + threadIdx.x;
    const float p = posv[i];
    const float c = (logf(s_row[i]) + C_OFF - p)
                  + (logf(s_col[i]) + C_OFF - p);

    float v = c;
    #pragma unroll
    for (int off = 32; off > 0; off >>= 1) v += __shfl_down(v, off, 64);
    if ((threadIdx.x & 63) == 0) atomicAdd(total, v);

    const unsigned long long m = __ballot(pid[i] != pid[0]);
    if (m != 0ull && (threadIdx.x & 63) == 0) atomicOr(flag, 1);

    __syncthreads();
    __threadfence();
    if (threadIdx.x == 0) {
        const int done = atomicAdd(cnt, 1);
        if (done == (int)gridDim.x - 1) {
            const float t = atomicAdd(total, 0.0f);
            const int   f = atomicOr(flag, 0);
            out[0] = f ? t / (2.0f * (float)BSZ) : 0.0f;
        }
    }
}

// ---------------------------------------------------------------- launcher
extern "C" void kernel_launch(void* const* d_in, const int* in_sizes, int n_in,
                              void* d_out, int out_size, void* d_ws, size_t ws_size,
                              hipStream_t stream)
{
    const float* za  = (const float*)d_in[0];
    const float* zt  = (const float*)d_in[1];
    const int*   pid = (const int*)d_in[2];
    float* out = (float*)d_out;

    // ws: za_f8 2MB | zt_perm 2MB | s_row[8192] s_col[8192] total flag cnt posv[8192]
    unsigned char* za_f8   = (unsigned char*)d_ws;
    unsigned char* zt_perm = za_f8 + (size_t)BSZ * DDIM;
    float*  s_row   = (float*)(zt_perm + (size_t)BSZ * DDIM);
    float*  s_col   = s_row + BSZ;
    float*  total   = s_col + BSZ;
    int*    flag    = (int*)(total + 1);
    int*    cnt     = flag + 1;
    float*  posv    = (float*)(cnt + 1);

    prep_kernel<<<dim3(2048), 256, 0, stream>>>(za, zt, za_f8, zt_perm, s_row);

    sim_fused<<<dim3(512), 256, 0, stream>>>(za_f8, zt_perm, pid,
                                             s_row, s_col, posv);

    finalize_rows<<<dim3(BSZ / 256), 256, 0, stream>>>(
        pid, s_row, s_col, posv, total, flag, cnt, out);
}